// Round 15
// baseline (1685.018 us; speedup 1.0000x reference)
//
#include <hip/hip_runtime.h>

typedef __attribute__((ext_vector_type(8))) short s8v;   // 8 x bf16 (4 VGPRs)
typedef __attribute__((ext_vector_type(4))) float f4v;   // MFMA accumulator

#define BB 8
#define TT 500
#define UU 120
#define UP1 121
#define VV 128
#define HH 320
#define G4 1280

// ---------------- helpers ----------------
__device__ __forceinline__ unsigned short f2bf(float x) {
  unsigned u = __builtin_bit_cast(unsigned, x);
  unsigned r = (u + 0x7FFFu + ((u >> 16) & 1u)) >> 16;  // RNE
  return (unsigned short)r;
}
__device__ __forceinline__ s8v ld8bf(const float* p) {  // 8 f32 -> s8v bf16
  s8v r;
#pragma unroll
  for (int j = 0; j < 8; j++) r[j] = (short)f2bf(p[j]);
  return r;
}
__device__ __forceinline__ float sigf(float x)   { return 1.f / (1.f + __expf(-x)); }
__device__ __forceinline__ float tanh_f(float x) { return 2.f / (1.f + __expf(-2.f * x)) - 1.f; }

// backoff with constant-arg s_sleep (builtin requires a literal)
__device__ __forceinline__ void backoff(int tries) {
  if (tries > 2) {
    if (tries < 10) __builtin_amdgcn_s_sleep(32);
    else            __builtin_amdgcn_s_sleep(127);
  }
}

// agent-scope (L3-coherent) relaxed atomics — proven transport
__device__ __forceinline__ unsigned ald32(const unsigned* p) {
  return __hip_atomic_load((unsigned*)p, __ATOMIC_RELAXED, __HIP_MEMORY_SCOPE_AGENT);
}
__device__ __forceinline__ void ast32(unsigned* p, unsigned v) {
  __hip_atomic_store(p, v, __ATOMIC_RELAXED, __HIP_MEMORY_SCOPE_AGENT);
}

// ---------------- prep: conversions + bias folds + xprojd + out-zero ----------------
__global__ __launch_bounds__(256) void prep_w(
    const float* __restrict__ wih0, const float* __restrict__ xs,
    const float* __restrict__ bih1, const float* __restrict__ bhh1,
    const float* __restrict__ bih0, const float* __restrict__ bhh0,
    const int* __restrict__ ys, const float* __restrict__ dWih,
    const float* __restrict__ dbih, const float* __restrict__ dbhh,
    ushort* __restrict__ wih0b, ushort* __restrict__ xsb,
    float* __restrict__ bias1p, float* __restrict__ b0s,
    float* __restrict__ xpd, float* __restrict__ out)
{
  if (blockIdx.x >= 1990) {                  // ---- xprojd section ----
    const int blk = blockIdx.x - 1990;       // 968 = 8 * 121
    const int b = blk / UP1, u = blk - b * UP1;
    int colv = -1;
    if (u > 0) colv = ys[b * UU + (u - 1)] - 1;
    for (int i = threadIdx.x; i < G4; i += 256) {
      int uu = i >> 2, gg = i & 3;
      int row = gg * HH + uu;
      float v = dbih[row] + dbhh[row];
      if (colv >= 0) v += dWih[row * 127 + colv];
      xpd[((size_t)b * UP1 + u) * G4 + i] = v;
    }
    return;
  }
  int i = blockIdx.x * blockDim.x + threadIdx.x;
  if (i == 0) out[0] = 0.f;
  if (i < 122880) {                          // Wih0 [1280][80] -> [1280][96] padded
    int row = i / 96, k = i - row * 96;
    wih0b[i] = (k < 80) ? f2bf(wih0[row * 80 + k]) : (ushort)0;
  } else if (i < 506880) {                   // xs [4000][80] -> [4000][96] padded
    int e = i - 122880;
    int row = e / 96, k = e - row * 96;
    xsb[e] = (k < 80) ? f2bf(xs[row * 80 + k]) : (ushort)0;
  } else if (i < 508160) {                   // bias1 permuted [unit][gate]
    int e = i - 506880;
    int uq = e >> 2, gq = e & 3;
    bias1p[e] = bih1[gq * HH + uq] + bhh1[gq * HH + uq];
  } else if (i < 509440) {                   // bih0+bhh0 summed (gate-row order)
    int e = i - 508160;
    b0s[e] = bih0[e] + bhh0[e];
  }
}

// ======================================================================
// Fused pipeline v11: ONE 256-block grid, 1 block/CU (103KB LDS), all
// co-resident by capacity. R13 structure + two changes:
//  (1) LSE worker polling backoff matched to the ~84us/cell production
//      rate (2 quick tries -> s_sleep(32) -> s_sleep(127)): kills the
//      ~100GB/s background poll traffic that cost the pipeline +105us.
//  (2) xproj0 moved into the worker prologue (tiles w, w+224, TAGGED f32
//      xp0); stage0 consumes xp0 via the SAME deferred tag-resolve proven
//      for stage1's xp1. The xproj0_mfma launch disappears.
//   wg 0-4: stage0 | 5-9: stage1 | 10-14: dec | 15-19: relay
//   wg 20-22: enc proj (tagged enc2) | 23: dec proj (tagged dec2)
//   wg 24-247: xproj0 prologue + LSE workers (tagged lb/ly)
//   wg 248-255: dp (tagged reads), one sample each.
// ======================================================================
__global__ __launch_bounds__(512, 1) void lstm_fused(
    const float* __restrict__ eWhh0, const float* __restrict__ eWih1,
    const float* __restrict__ eWhh1, const float* __restrict__ dWhh,
    const float* __restrict__ b1p,
    float* __restrict__ xp0, const float* __restrict__ xpd,
    unsigned* __restrict__ h0u, unsigned* __restrict__ h1u, unsigned* __restrict__ hdu,
    unsigned* __restrict__ xp1u,
    const float* __restrict__ eWo, const float* __restrict__ dWo,
    const float* __restrict__ ebo, const float* __restrict__ dbo,
    float* __restrict__ enc2, float* __restrict__ dec2,
    float* __restrict__ lbp, float* __restrict__ lyp,
    const int* __restrict__ ys, const int* __restrict__ xlen,
    const int* __restrict__ ylen, float* __restrict__ out,
    const ushort* __restrict__ xsb, const ushort* __restrict__ wih0b,
    const float* __restrict__ b0s)
{
  __shared__ ushort hbS[2][16][328];         // 21KB  h double-buffer [b][u]
  __shared__ s8v wlds[8][10][64];            // 80KB  tile1 weight frags / proj Wo

  const int wg = blockIdx.x;
  const int tid = threadIdx.x;
  const int wave = tid >> 6, lane = tid & 63;
  const int q = lane >> 4, n16 = lane & 15;
  const int uloc = n16 >> 2, g = n16 & 3;
  const int bcol = n16 & 7;
  const bool act = (n16 < BB);

  if (wg >= 248) {
    // ================= dp: RNN-T forward DP, one sample per block =================
    if (tid >= 64) return;
    const int b = wg - 248;
    const int l = tid;
    const int u0 = 2 * l, u1 = 2 * l + 1;
    const int tl = xlen[b], ul = ylen[b];
    const float NEG = -1e30f;
    const unsigned* lbu = (const unsigned*)lbp;
    const unsigned* lyu = (const unsigned*)lyp;
    float alpha0 = (l == 0) ? 0.f : NEG;
    float alpha1 = NEG;

    int pt0 = 1 - u0, pt1 = 1 - u1;
    bool vb0 = (u0 <= UU && pt0 >= 1 && pt0 < TT);
    bool vy0 = (u0 >= 1 && u0 <= UU && pt0 >= 0 && pt0 < TT);
    bool vb1 = (u1 <= UU && pt1 >= 1 && pt1 < TT);
    bool vy1 = (u1 >= 1 && u1 <= UU && pt1 >= 0 && pt1 < TT);
    unsigned nb0 = vb0 ? ald32(lbu + ((size_t)b * TT + pt0 - 1) * UP1 + u0) : 1u;
    unsigned ny0 = vy0 ? ald32(lyu + ((size_t)b * TT + pt0) * UU + (u0 - 1)) : 1u;
    unsigned nb1 = vb1 ? ald32(lbu + ((size_t)b * TT + pt1 - 1) * UP1 + u1) : 1u;
    unsigned ny1 = vy1 ? ald32(lyu + ((size_t)b * TT + pt1) * UU + (u1 - 1)) : 1u;

    for (int d = 1; d <= TT - 1 + UU; d++) {
      {
        int tries = 0;
        for (;;) {
          unsigned m = nb0 & ny0 & nb1 & ny1;
          if (__all((int)(m & 1u)) || ++tries > (1 << 15)) break;
          if (tries > 8) __builtin_amdgcn_s_sleep(8);
          int t0 = d - u0, t1 = d - u1;
          if (vb0) nb0 = ald32(lbu + ((size_t)b * TT + t0 - 1) * UP1 + u0);
          if (vy0) ny0 = ald32(lyu + ((size_t)b * TT + t0) * UU + (u0 - 1));
          if (vb1) nb1 = ald32(lbu + ((size_t)b * TT + t1 - 1) * UP1 + u1);
          if (vy1) ny1 = ald32(lyu + ((size_t)b * TT + t1) * UU + (u1 - 1));
        }
      }
      float lb0 = vb0 ? __uint_as_float(nb0 & ~1u) : 0.f;
      float ly0 = vy0 ? __uint_as_float(ny0 & ~1u) : 0.f;
      float lb1 = vb1 ? __uint_as_float(nb1 & ~1u) : 0.f;
      float ly1 = vy1 ? __uint_as_float(ny1 & ~1u) : 0.f;
      pt0 = (d + 1) - u0; pt1 = (d + 1) - u1;
      vb0 = (u0 <= UU && pt0 >= 1 && pt0 < TT);
      vy0 = (u0 >= 1 && u0 <= UU && pt0 >= 0 && pt0 < TT);
      vb1 = (u1 <= UU && pt1 >= 1 && pt1 < TT);
      vy1 = (u1 >= 1 && u1 <= UU && pt1 >= 0 && pt1 < TT);
      nb0 = vb0 ? ald32(lbu + ((size_t)b * TT + pt0 - 1) * UP1 + u0) : 1u;
      ny0 = vy0 ? ald32(lyu + ((size_t)b * TT + pt0) * UU + (u0 - 1)) : 1u;
      nb1 = vb1 ? ald32(lbu + ((size_t)b * TT + pt1 - 1) * UP1 + u1) : 1u;
      ny1 = vy1 ? ald32(lyu + ((size_t)b * TT + pt1) * UU + (u1 - 1)) : 1u;

      float am1 = __shfl_up(alpha1, 1);
      float old0 = alpha0, old1 = alpha1;
      int t0 = d - u0;
      if (u0 <= UU && t0 >= 0 && t0 < TT) {
        float a1 = (t0 >= 1) ? old0 + lb0 : NEG;
        float a2 = (u0 >= 1) ? am1 + ly0 : NEG;
        float m = fmaxf(a1, a2);
        float val = (m <= -1e29f) ? NEG : m + __logf(1.f + __expf(-fabsf(a1 - a2)));
        alpha0 = val;
        if (t0 == tl - 1 && u0 == ul) {
          unsigned lt; int tr = 0;
          for (;;) { lt = ald32(lbu + ((size_t)b * TT + t0) * UP1 + u0);
                     if ((lt & 1u) || ++tr > (1 << 15)) break;
                     __builtin_amdgcn_s_sleep(8); }
          atomicAdd(out, -0.125f * (val + __uint_as_float(lt & ~1u)));
        }
      }
      int t1 = d - u1;
      if (u1 <= UU && t1 >= 0 && t1 < TT) {
        float a1 = (t1 >= 1) ? old1 + lb1 : NEG;
        float a2 = old0 + ly1;                 // u1 odd => u1>=1 always
        float m = fmaxf(a1, a2);
        float val = (m <= -1e29f) ? NEG : m + __logf(1.f + __expf(-fabsf(a1 - a2)));
        alpha1 = val;
        if (t1 == tl - 1 && u1 == ul) {
          unsigned lt; int tr = 0;
          for (;;) { lt = ald32(lbu + ((size_t)b * TT + t1) * UP1 + u1);
                     if ((lt & 1u) || ++tr > (1 << 15)) break;
                     __builtin_amdgcn_s_sleep(8); }
          atomicAdd(out, -0.125f * (val + __uint_as_float(lt & ~1u)));
        }
      }
    }
    return;
  }

  if (wg >= 24) {
    // ================= xproj0 prologue: tiles mt = w0, w0+224 (TAGGED xp0) =================
    const int w0 = wg - 24;
    for (int mt = w0; mt < 250; mt += 224) {
      s8v a[3];
#pragma unroll
      for (int kt = 0; kt < 3; kt++)
        a[kt] = *(const s8v*)(xsb + (mt * 16 + n16) * 96 + kt * 32 + q * 8);
      for (int nt = wave; nt < 80; nt += 8) {
        s8v bf[3];
#pragma unroll
        for (int kt = 0; kt < 3; kt++)
          bf[kt] = *(const s8v*)(wih0b + (nt * 16 + n16) * 96 + kt * 32 + q * 8);
        f4v acc = {0.f, 0.f, 0.f, 0.f};
#pragma unroll
        for (int kt = 0; kt < 3; kt++)
          acc = __builtin_amdgcn_mfma_f32_16x16x32_bf16(a[kt], bf[kt], acc, 0, 0, 0);
        const int gr = nt * 16 + n16;        // D col = gate row
        const int gg = gr / HH;
        const int uu = gr - gg * HH;
        const float bias = b0s[gr];
#pragma unroll
        for (int r = 0; r < 4; r++) {
          int bt = mt * 16 + 4 * q + r;      // D row = (b,t) row
          ast32((unsigned*)&xp0[(size_t)bt * G4 + uu * 4 + gg],
                __float_as_uint(acc[r] + bias) | 1u);
        }
      }
    }

    // ================= LSE workers: cells c = w0, w0+224, ... (t-major) =================
    const unsigned* e2u = (const unsigned*)enc2;
    const unsigned* d2u = (const unsigned*)dec2;
    for (int c = w0; c < 4000; c += 224) {
      const int t = c >> 3, b = c & 7;
      const unsigned* er = e2u + ((size_t)t * 16 + b) * VV;
      unsigned ev0, ev1;
      {
        int tries = 0;
        for (;;) {
          ev0 = ald32(er + lane); ev1 = ald32(er + lane + 64);
          if (__all((int)(ev0 & ev1 & 1u)) || ++tries > (1 << 13)) break;
          backoff(tries);
        }
      }
      const float e0 = __uint_as_float(ev0 & ~1u);
      const float e1 = __uint_as_float(ev1 & ~1u);
      for (int u = wave; u < UP1; u += 8) {
        const unsigned* dr = d2u + ((size_t)u * 16 + b) * VV;
        unsigned dv0, dv1;
        int tr2 = 0;
        for (;;) {
          dv0 = ald32(dr + lane); dv1 = ald32(dr + lane + 64);
          if (__all((int)(dv0 & dv1 & 1u)) || ++tr2 > (1 << 13)) break;
          backoff(tr2);
        }
        float s0 = e0 + __uint_as_float(dv0 & ~1u);
        float s1 = e1 + __uint_as_float(dv1 & ~1u);
        float mx = fmaxf(s0, s1);
#pragma unroll
        for (int off = 32; off >= 1; off >>= 1) mx = fmaxf(mx, __shfl_xor(mx, off));
        float p = __expf(s0 - mx) + __expf(s1 - mx);
#pragma unroll
        for (int off = 32; off >= 1; off >>= 1) p += __shfl_xor(p, off);
        float lsev = mx + __logf(p);
        if (u < UU) {
          int y = ys[b * UU + u];              // in [1,127]
          float sy = (y < 64) ? __shfl(s0, y) : __shfl(s1, y - 64);
          if (lane == 0)
            ast32((unsigned*)(lyp + ((size_t)b * TT + t) * UU + u),
                  __float_as_uint(sy - lsev) | 1u);
        }
        if (lane == 0)
          ast32((unsigned*)(lbp + ((size_t)b * TT + t) * UP1 + u),
                __float_as_uint(s0 - lsev) | 1u);
      }
    }
    return;
  }

  // zero both LDS h buffers (pipeline branches only)
  for (int i = tid; i < 2 * 16 * 328; i += 512) ((ushort*)hbS)[i] = 0;

  if (wg >= 20) {
    // ================= streaming output projections (TAGGED outputs) =================
    const bool isenc = (wg < 23);
    const unsigned* hsrc = isenc ? h1u : hdu;
    const float* wsrc = isenc ? eWo : dWo;   // f32, converted on stage-in
    const float* bsrc = isenc ? ebo : dbo;
    float* osrc = isenc ? enc2 : dec2;
    const int tstart = isenc ? (wg - 20) : 0;
    const int tstep = isenc ? 3 : 1;
    const int tmax = isenc ? TT : UP1;
    ushort* wl = (ushort*)wlds;
    for (int i = tid; i < 40960; i += 512) wl[i] = f2bf(wsrc[i]);
    __syncthreads();
    const int nt = wave;                     // 8 col-tiles of 16
    const int vc = nt * 16 + n16;
    const float bias = bsrc[vc];
    s8v bf[10];
#pragma unroll
    for (int kt = 0; kt < 10; kt++)
      bf[kt] = *(const s8v*)(wl + (size_t)vc * HH + kt * 32 + q * 8);

    for (int t = tstart; t < tmax; t += tstep) {
      const unsigned* src = hsrc + (size_t)(t + 1) * 2560 + wave * 320 + lane;
      unsigned v[5];
#pragma unroll
      for (int j = 0; j < 5; j++) v[j] = ald32(src + j * 64);
      int tries = 0;
      for (;;) {
        unsigned a = v[0] & v[1] & v[2] & v[3] & v[4];
        if (__all((int)(a & 1u)) || ++tries > (1 << 17)) break;
        if (tries > 64) __builtin_amdgcn_s_sleep(1);
#pragma unroll
        for (int j = 0; j < 5; j++) v[j] = ald32(src + j * 64);
      }
#pragma unroll
      for (int j = 0; j < 5; j++) {
        int f = wave * 320 + j * 64 + lane;            // u = f>>3, b = f&7
        hbS[0][f & 7][f >> 3] = (ushort)(v[j] >> 16);
      }
      __syncthreads();
      s8v a[10];
#pragma unroll
      for (int kt = 0; kt < 10; kt++)
        a[kt] = *(const s8v*)&hbS[0][n16][kt * 32 + q * 8];
      f4v acc = {0.f, 0.f, 0.f, 0.f};
#pragma unroll
      for (int kt = 0; kt < 10; kt++)
        acc = __builtin_amdgcn_mfma_f32_16x16x32_bf16(a[kt], bf[kt], acc, 0, 0, 0);
      if (q < 2) {
#pragma unroll
        for (int r = 0; r < 4; r++) {
          int b = 4 * q + r;                 // D row = batch
          ast32((unsigned*)&osrc[((size_t)t * 16 + b) * VV + vc],
                __float_as_uint(acc[r] + bias) | 1u);
        }
      }
      __syncthreads();                       // before next t overwrites hbS
    }
    return;
  }

  if (wg >= 15) {
    // ================= relay: xp1[s] = Wih1 @ h0[s+1] + b1 =================
    const int rw = wg - 15;
    const int w = rw * 8 + wave;
    const int ubase = w * 8;
    s8v afr0[10];
    {
      const int arow0 = g * HH + ubase + uloc;
      const int arow1 = g * HH + ubase + 4 + uloc;
#pragma unroll
      for (int kt = 0; kt < 10; kt++) {
        afr0[kt] = ld8bf(eWih1 + (size_t)arow0 * HH + kt * 32 + q * 8);
        wlds[wave][kt][lane] = ld8bf(eWih1 + (size_t)arow1 * HH + kt * 32 + q * 8);
      }
    }
    f4v bias4[2];
#pragma unroll
    for (int tile = 0; tile < 2; tile++)
      bias4[tile] = *(const f4v*)(b1p + (ubase + tile * 4 + q) * 4);

    unsigned v[5];
    {
      const unsigned* p = h0u + 2560 + wave * 320 + lane;
#pragma unroll
      for (int j = 0; j < 5; j++) v[j] = ald32(p + j * 64);
    }
    __syncthreads();                         // weight-LDS + hbS zeros visible

    for (int s = 0; s < TT; s++) {
      const int pb = s & 1;
      {
        const unsigned* p = h0u + (size_t)(s + 1) * 2560 + wave * 320 + lane;
        int tries = 0;
        for (;;) {
          unsigned a = v[0] & v[1] & v[2] & v[3] & v[4];
          if (__all((int)(a & 1u)) || ++tries > (1 << 17)) break;
          if (tries > 64) __builtin_amdgcn_s_sleep(1);
#pragma unroll
          for (int j = 0; j < 5; j++) v[j] = ald32(p + j * 64);
        }
#pragma unroll
        for (int j = 0; j < 5; j++) {
          int f = wave * 320 + j * 64 + lane;          // u = f>>3, b = f&7
          hbS[pb][f & 7][f >> 3] = (ushort)(v[j] >> 16);
        }
      }
      __syncthreads();
      if (s + 1 < TT) {
        const unsigned* p = h0u + (size_t)(s + 2) * 2560 + wave * 320 + lane;
#pragma unroll
        for (int j = 0; j < 5; j++) v[j] = ald32(p + j * 64);
      }

      f4v acc[2];
      acc[0] = bias4[0]; acc[1] = bias4[1];
#pragma unroll
      for (int kt = 0; kt < 10; kt++) {
        s8v b = *(const s8v*)&hbS[pb][n16][kt * 32 + q * 8];
        acc[0] = __builtin_amdgcn_mfma_f32_16x16x32_bf16(afr0[kt], b, acc[0], 0, 0, 0);
        s8v a1 = wlds[wave][kt][lane];
        acc[1] = __builtin_amdgcn_mfma_f32_16x16x32_bf16(a1, b, acc[1], 0, 0, 0);
      }
      if (act) {
#pragma unroll
        for (int tile = 0; tile < 2; tile++) {
          unsigned* dp = xp1u + (size_t)((unsigned)s * 8u + (unsigned)n16) * G4
                       + (unsigned)((ubase + tile * 4 + q) * 4);
#pragma unroll
          for (int r = 0; r < 4; r++)
            ast32(dp + r, __float_as_uint(acc[tile][r]) | 1u);   // LSB tag on f32
        }
      }
    }
    return;
  }

  // ================= recurrent stages =================
  const int stage = wg / 5;
  const int gw = wg - stage * 5;
  const int w = gw * 8 + wave;              // wave-in-stage [0,40)
  const int ubase = w * 8;                  // this wave owns units [ubase, ubase+8)

  const float* Af = (stage == 0) ? eWhh0 : ((stage == 1) ? eWhh1 : dWhh);
  // tile0 -> regs (40 VGPR), tile1 -> LDS; converted inline from f32
  s8v afr0[10];
  {
    const int arow0 = g * HH + ubase + uloc;
    const int arow1 = g * HH + ubase + 4 + uloc;
#pragma unroll
    for (int kt = 0; kt < 10; kt++) {
      afr0[kt] = ld8bf(Af + (size_t)arow0 * HH + kt * 32 + q * 8);
      wlds[wave][kt][lane] = ld8bf(Af + (size_t)arow1 * HH + kt * 32 + q * 8);
    }
  }

  const int steps = (stage == 2) ? UP1 : TT;
  unsigned* hio = (stage == 0) ? h0u : ((stage == 1) ? h1u : hdu);

  const float* xq = 0;
  if (stage == 2) xq = xpd + (size_t)bcol * UP1 * G4;

  float c0 = 0.f, c1 = 0.f;
  unsigned hv5[5];                           // in-flight bulk h reads
  __syncthreads();                           // LDS zeros + weight-LDS visible

  for (int t = 0; t < steps; t++) {
    const int pb = t & 1;

    // ---- pre-issue C-init inputs; consumed after the MFMA block ----
    f4v xq4[2];
    unsigned xv[2][4];
    if (stage == 2) {
#pragma unroll
      for (int tile = 0; tile < 2; tile++)
        xq4[tile] = *(const f4v*)(xq + (size_t)t * G4 + (ubase + tile * 4 + q) * 4);
    } else {
      const unsigned* xpp_base = (stage == 0)
          ? (const unsigned*)xp0 + (size_t)((unsigned)bcol * TT + (unsigned)t) * G4
          : xp1u + (size_t)((unsigned)t * 8u + (unsigned)bcol) * G4;
#pragma unroll
      for (int tile = 0; tile < 2; tile++)
#pragma unroll
        for (int r = 0; r < 4; r++)
          xv[tile][r] = ald32(xpp_base + (ubase + tile * 4 + q) * 4 + r);
    }

    // ---- resolve pre-issued bulk h[t] reads, transpose-relay into LDS ----
    if (t > 0) {
      const unsigned* src = hio + (size_t)t * 2560 + wave * 320 + lane;
      int tries = 0;
      for (;;) {
        unsigned a = hv5[0] & hv5[1] & hv5[2] & hv5[3] & hv5[4];
        if (__all((int)(a & 1u)) || ++tries > (1 << 17)) break;
        if (tries > 64) __builtin_amdgcn_s_sleep(1);
#pragma unroll
        for (int j = 0; j < 5; j++) hv5[j] = ald32(src + j * 64);
      }
#pragma unroll
      for (int j = 0; j < 5; j++) {
        int f = wave * 320 + j * 64 + lane;            // u = f>>3, b = f&7
        hbS[pb][f & 7][f >> 3] = (ushort)(hv5[j] >> 16);
      }
    }
    __syncthreads();

    // ---- MFMAs: B-frags from LDS h(t); tile1 A-frags from LDS ----
    f4v acc[2];
    acc[0] = (f4v){0.f, 0.f, 0.f, 0.f};
    acc[1] = (f4v){0.f, 0.f, 0.f, 0.f};
#pragma unroll
    for (int kt = 0; kt < 10; kt++) {
      s8v b = *(const s8v*)&hbS[pb][n16][kt * 32 + q * 8];
      acc[0] = __builtin_amdgcn_mfma_f32_16x16x32_bf16(afr0[kt], b, acc[0], 0, 0, 0);
      s8v a1 = wlds[wave][kt][lane];
      acc[1] = __builtin_amdgcn_mfma_f32_16x16x32_bf16(a1, b, acc[1], 0, 0, 0);
    }

    // ---- resolve C-init (deferred; stage0/1 tag-spin on xp0/xp1) ----
    if (stage == 2) {
#pragma unroll
      for (int tile = 0; tile < 2; tile++) {
        acc[tile][0] += xq4[tile][0]; acc[tile][1] += xq4[tile][1];
        acc[tile][2] += xq4[tile][2]; acc[tile][3] += xq4[tile][3];
      }
    } else {
      const unsigned* xpp_base = (stage == 0)
          ? (const unsigned*)xp0 + (size_t)((unsigned)bcol * TT + (unsigned)t) * G4
          : xp1u + (size_t)((unsigned)t * 8u + (unsigned)bcol) * G4;
      int tries = 0;
      for (;;) {
        unsigned m = xv[0][0] & xv[0][1] & xv[0][2] & xv[0][3]
                   & xv[1][0] & xv[1][1] & xv[1][2] & xv[1][3];
        bool ok = (!act) || ((m & 1u) != 0u);
        if (__all((int)ok) || ++tries > (1 << 17)) break;
        if (tries > 64) __builtin_amdgcn_s_sleep(1);
#pragma unroll
        for (int tile = 0; tile < 2; tile++)
#pragma unroll
          for (int r = 0; r < 4; r++)
            xv[tile][r] = ald32(xpp_base + (ubase + tile * 4 + q) * 4 + r);
      }
#pragma unroll
      for (int tile = 0; tile < 2; tile++)
#pragma unroll
        for (int r = 0; r < 4; r++)
          acc[tile][r] += __uint_as_float(xv[tile][r] & ~1u);
    }

    // ---- lane-local LSTM cell ----
    float hv0, hv1;
    {
      float ig = sigf(acc[0][0]), fg = sigf(acc[0][1]);
      float gv = tanh_f(acc[0][2]), og = sigf(acc[0][3]);
      c0 = fg * c0 + ig * gv; hv0 = og * tanh_f(c0);
    }
    {
      float ig = sigf(acc[1][0]), fg = sigf(acc[1][1]);
      float gv = tanh_f(acc[1][2]), og = sigf(acc[1][3]);
      c1 = fg * c1 + ig * gv; hv1 = og * tanh_f(c1);
    }
    if (act) {
      // packed [u][b] store: wave's 16 stores span 2-4 cache lines; no drain
      unsigned* dst = hio + (size_t)(t + 1) * 2560;
      ast32(dst + (ubase + q) * 8 + n16,     (((unsigned)f2bf(hv0)) << 16) | 1u);
      ast32(dst + (ubase + 4 + q) * 8 + n16, (((unsigned)f2bf(hv1)) << 16) | 1u);
    }

    // ---- issue next step's bulk h reads: flight overlaps store landing ----
    if (t + 1 < steps) {
      const unsigned* src = hio + (size_t)(t + 1) * 2560 + wave * 320 + lane;
#pragma unroll
      for (int j = 0; j < 5; j++) hv5[j] = ald32(src + j * 64);
    }
  }
}

// ---------------- launch ----------------
extern "C" void kernel_launch(void* const* d_in, const int* in_sizes, int n_in,
                              void* d_out, int out_size, void* d_ws, size_t ws_size,
                              hipStream_t stream) {
  (void)in_sizes; (void)n_in; (void)out_size;
  const float* xs    = (const float*)d_in[0];
  const int*   ys    = (const int*)d_in[1];
  const int*   xlen  = (const int*)d_in[2];
  const int*   ylen  = (const int*)d_in[3];
  const float* eWih0 = (const float*)d_in[4];
  const float* eWhh0 = (const float*)d_in[5];
  const float* ebih0 = (const float*)d_in[6];
  const float* ebhh0 = (const float*)d_in[7];
  const float* eWih1 = (const float*)d_in[8];
  const float* eWhh1 = (const float*)d_in[9];
  const float* ebih1 = (const float*)d_in[10];
  const float* ebhh1 = (const float*)d_in[11];
  const float* eWo   = (const float*)d_in[12];
  const float* ebo   = (const float*)d_in[13];
  const float* dWih  = (const float*)d_in[15];
  const float* dWhh  = (const float*)d_in[16];
  const float* dbih  = (const float*)d_in[17];
  const float* dbhh  = (const float*)d_in[18];
  const float* dWo   = (const float*)d_in[19];
  const float* dbo   = (const float*)d_in[20];

  char* ws = (char*)d_ws;
  const size_t OFF_XP0   = 1024;
  const size_t OFF_XPD   = OFF_XP0   + 20480000;  // 8*500*1280 tagged f32
  const size_t OFF_H0    = OFF_XPD   + 4956160;   // 501 * 2560 u32 (tagged, [u][b])
  const size_t OFF_H1    = OFF_H0    + 5130240;
  const size_t OFF_HD    = OFF_H1    + 5130240;   // 122 * 2560 u32
  const size_t OFF_WIH0B = OFF_HD    + 1249280;   // 1280*96 bf16
  const size_t OFF_XSB   = OFF_WIH0B + 245760;    // 4000*96 bf16
  const size_t OFF_B1P   = OFF_XSB   + 768000;
  const size_t OFF_B0S   = OFF_B1P   + 5120;
  const size_t OFF_ENC2  = OFF_B0S   + 5120;
  const size_t OFF_DEC2  = OFF_ENC2  + 4096000;   // 500*16*128 tagged f32
  const size_t OFF_LB    = OFF_DEC2  + 991232;    // 121*16*128 tagged f32
  const size_t OFF_LY    = OFF_LB    + 1936000;   // 8*500*121 tagged f32
  const size_t OFF_XP1   = OFF_LY    + 1920000;   // 500*8*1280 tagged f32
  const size_t TOTAL     = OFF_XP1   + 20480000;
  if (ws_size < TOTAL) return;

  float*    xp0   = (float*)(ws + OFF_XP0);
  float*    xpd   = (float*)(ws + OFF_XPD);
  unsigned* h0    = (unsigned*)(ws + OFF_H0);
  unsigned* h1    = (unsigned*)(ws + OFF_H1);
  unsigned* hd    = (unsigned*)(ws + OFF_HD);
  ushort*   wih0b = (ushort*)(ws + OFF_WIH0B);
  ushort*   xsb   = (ushort*)(ws + OFF_XSB);
  float*    b1p   = (float*)(ws + OFF_B1P);
  float*    b0s   = (float*)(ws + OFF_B0S);
  float*    enc2  = (float*)(ws + OFF_ENC2);
  float*    dec2  = (float*)(ws + OFF_DEC2);
  float*    lb    = (float*)(ws + OFF_LB);
  float*    ly    = (float*)(ws + OFF_LY);
  unsigned* xp1   = (unsigned*)(ws + OFF_XP1);
  float*    out   = (float*)d_out;

  hipLaunchKernelGGL(prep_w, dim3(2958), dim3(256), 0, stream,
                     eWih0, xs, ebih1, ebhh1, ebih0, ebhh0,
                     ys, dWih, dbih, dbhh,
                     wih0b, xsb, b1p, b0s, xpd, out);
  hipLaunchKernelGGL(lstm_fused, dim3(256), dim3(512), 0, stream,
                     eWhh0, eWih1, eWhh1, dWhh, b1p, xp0, xpd, h0, h1, hd, xp1,
                     eWo, dWo, ebo, dbo, enc2, dec2, lb, ly,
                     ys, xlen, ylen, out, xsb, wih0b, b0s);
}

// Round 16
// 1682.053 us; speedup vs baseline: 1.0018x; 1.0018x over previous
//
#include <hip/hip_runtime.h>

typedef __attribute__((ext_vector_type(8))) short s8v;   // 8 x bf16 (4 VGPRs)
typedef __attribute__((ext_vector_type(4))) float f4v;   // MFMA accumulator

#define BB 8
#define TT 500
#define UU 120
#define UP1 121
#define VV 128
#define HH 320
#define G4 1280

// ---------------- helpers ----------------
__device__ __forceinline__ unsigned short f2bf(float x) {
  unsigned u = __builtin_bit_cast(unsigned, x);
  unsigned r = (u + 0x7FFFu + ((u >> 16) & 1u)) >> 16;  // RNE
  return (unsigned short)r;
}
__device__ __forceinline__ s8v ld8bf(const float* p) {  // 8 f32 -> s8v bf16
  s8v r;
#pragma unroll
  for (int j = 0; j < 8; j++) r[j] = (short)f2bf(p[j]);
  return r;
}
__device__ __forceinline__ float sigf(float x)   { return 1.f / (1.f + __expf(-x)); }
__device__ __forceinline__ float tanh_f(float x) { return 2.f / (1.f + __expf(-2.f * x)) - 1.f; }

// backoff with constant-arg s_sleep (builtin requires a literal)
__device__ __forceinline__ void backoff(int tries) {
  if (tries > 2) {
    if (tries < 10) __builtin_amdgcn_s_sleep(32);
    else            __builtin_amdgcn_s_sleep(127);
  }
}

// agent-scope (L3-coherent) relaxed atomics — proven transport
__device__ __forceinline__ unsigned ald32(const unsigned* p) {
  return __hip_atomic_load((unsigned*)p, __ATOMIC_RELAXED, __HIP_MEMORY_SCOPE_AGENT);
}
__device__ __forceinline__ void ast32(unsigned* p, unsigned v) {
  __hip_atomic_store(p, v, __ATOMIC_RELAXED, __HIP_MEMORY_SCOPE_AGENT);
}

// ---------------- prep: conversions + bias folds + xprojd + out-zero ----------------
__global__ __launch_bounds__(256) void prep_w(
    const float* __restrict__ wih0, const float* __restrict__ xs,
    const float* __restrict__ bih1, const float* __restrict__ bhh1,
    const float* __restrict__ bih0, const float* __restrict__ bhh0,
    const int* __restrict__ ys, const float* __restrict__ dWih,
    const float* __restrict__ dbih, const float* __restrict__ dbhh,
    ushort* __restrict__ wih0b, ushort* __restrict__ xsb,
    float* __restrict__ bias1p, float* __restrict__ b0s,
    float* __restrict__ xpd, float* __restrict__ out)
{
  if (blockIdx.x >= 1990) {                  // ---- xprojd section ----
    const int blk = blockIdx.x - 1990;       // 968 = 8 * 121
    const int b = blk / UP1, u = blk - b * UP1;
    int colv = -1;
    if (u > 0) colv = ys[b * UU + (u - 1)] - 1;
    for (int i = threadIdx.x; i < G4; i += 256) {
      int uu = i >> 2, gg = i & 3;
      int row = gg * HH + uu;
      float v = dbih[row] + dbhh[row];
      if (colv >= 0) v += dWih[row * 127 + colv];
      xpd[((size_t)b * UP1 + u) * G4 + i] = v;
    }
    return;
  }
  int i = blockIdx.x * blockDim.x + threadIdx.x;
  if (i == 0) out[0] = 0.f;
  if (i < 122880) {                          // Wih0 [1280][80] -> [1280][96] padded
    int row = i / 96, k = i - row * 96;
    wih0b[i] = (k < 80) ? f2bf(wih0[row * 80 + k]) : (ushort)0;
  } else if (i < 506880) {                   // xs [4000][80] -> [4000][96] padded
    int e = i - 122880;
    int row = e / 96, k = e - row * 96;
    xsb[e] = (k < 80) ? f2bf(xs[row * 80 + k]) : (ushort)0;
  } else if (i < 508160) {                   // bias1 permuted [unit][gate]
    int e = i - 506880;
    int uq = e >> 2, gq = e & 3;
    bias1p[e] = bih1[gq * HH + uq] + bhh1[gq * HH + uq];
  } else if (i < 509440) {                   // bih0+bhh0 summed (gate-row order)
    int e = i - 508160;
    b0s[e] = bih0[e] + bhh0[e];
  }
}

// ---------------- xproj for layer0: [4000,96]bf16 @ [96,1280] -> xp0[b][t][u][g] f32 ----------------
__global__ __launch_bounds__(256) void xproj0_mfma(
    const ushort* __restrict__ xsb, const ushort* __restrict__ wih0b,
    const float* __restrict__ b0s, float* __restrict__ xp0)
{
  const int mt = blockIdx.x;                 // 250 tiles of 16 (b,t)-rows
  const int wave = threadIdx.x >> 6, lane = threadIdx.x & 63;
  const int q = lane >> 4, n16 = lane & 15;
  s8v a[3];
#pragma unroll
  for (int kt = 0; kt < 3; kt++)
    a[kt] = *(const s8v*)(xsb + (mt * 16 + n16) * 96 + kt * 32 + q * 8);
  for (int nt = wave; nt < 80; nt += 4) {
    s8v bf[3];
#pragma unroll
    for (int kt = 0; kt < 3; kt++)
      bf[kt] = *(const s8v*)(wih0b + (nt * 16 + n16) * 96 + kt * 32 + q * 8);
    f4v acc = {0.f, 0.f, 0.f, 0.f};
#pragma unroll
    for (int kt = 0; kt < 3; kt++)
      acc = __builtin_amdgcn_mfma_f32_16x16x32_bf16(a[kt], bf[kt], acc, 0, 0, 0);
    const int gr = nt * 16 + n16;            // D col = gate row
    const int gg = gr / HH;
    const int uu = gr - gg * HH;
    const float bias = b0s[gr];
#pragma unroll
    for (int r = 0; r < 4; r++) {
      int bt = mt * 16 + 4 * q + r;          // D row = (b,t) row
      xp0[(size_t)bt * G4 + uu * 4 + gg] = acc[r] + bias;
    }
  }
}

// ======================================================================
// Fused pipeline v12 = best-of R13/R15: ONE 256-block grid (1 block/CU,
// co-resident by capacity), LSE worker BACKOFF kept (R15: −22us dispatch),
// xproj0 fusion REVERTED (R15: +80MB scattered tagged writes during the
// pipeline window; xp0 returns to a clean pre-pipeline kernel, stage0 does
// plain pre-issued f4v C-init loads — R12-proven path).
//   wg 0-4: stage0 | 5-9: stage1 | 10-14: dec | 15-19: relay
//   wg 20-22: enc proj (tagged enc2) | 23: dec proj (tagged dec2)
//   wg 24-247: LSE workers (tagged lb/ly, rate-matched backoff)
//   wg 248-255: dp (tagged reads), one sample each.
// Structural floor note: the recurrence clock is ~3us/step (store-land +
// cross-CU detect/read via L3 + compute) x 500 steps ~= 1.5ms; breaking it
// needs same-CU stacking (refuted R4/R5: allocator) or same-L2 colocation
// (refuted R2: poll concentration) — this design is at that floor.
// ======================================================================
__global__ __launch_bounds__(512, 1) void lstm_fused(
    const float* __restrict__ eWhh0, const float* __restrict__ eWih1,
    const float* __restrict__ eWhh1, const float* __restrict__ dWhh,
    const float* __restrict__ b1p,
    const float* __restrict__ xp0, const float* __restrict__ xpd,
    unsigned* __restrict__ h0u, unsigned* __restrict__ h1u, unsigned* __restrict__ hdu,
    unsigned* __restrict__ xp1u,
    const float* __restrict__ eWo, const float* __restrict__ dWo,
    const float* __restrict__ ebo, const float* __restrict__ dbo,
    float* __restrict__ enc2, float* __restrict__ dec2,
    float* __restrict__ lbp, float* __restrict__ lyp,
    const int* __restrict__ ys, const int* __restrict__ xlen,
    const int* __restrict__ ylen, float* __restrict__ out)
{
  __shared__ ushort hbS[2][16][328];         // 21KB  h double-buffer [b][u]
  __shared__ s8v wlds[8][10][64];            // 80KB  tile1 weight frags / proj Wo

  const int wg = blockIdx.x;
  const int tid = threadIdx.x;
  const int wave = tid >> 6, lane = tid & 63;
  const int q = lane >> 4, n16 = lane & 15;
  const int uloc = n16 >> 2, g = n16 & 3;
  const int bcol = n16 & 7;
  const bool act = (n16 < BB);

  if (wg >= 248) {
    // ================= dp: RNN-T forward DP, one sample per block =================
    if (tid >= 64) return;
    const int b = wg - 248;
    const int l = tid;
    const int u0 = 2 * l, u1 = 2 * l + 1;
    const int tl = xlen[b], ul = ylen[b];
    const float NEG = -1e30f;
    const unsigned* lbu = (const unsigned*)lbp;
    const unsigned* lyu = (const unsigned*)lyp;
    float alpha0 = (l == 0) ? 0.f : NEG;
    float alpha1 = NEG;

    int pt0 = 1 - u0, pt1 = 1 - u1;
    bool vb0 = (u0 <= UU && pt0 >= 1 && pt0 < TT);
    bool vy0 = (u0 >= 1 && u0 <= UU && pt0 >= 0 && pt0 < TT);
    bool vb1 = (u1 <= UU && pt1 >= 1 && pt1 < TT);
    bool vy1 = (u1 >= 1 && u1 <= UU && pt1 >= 0 && pt1 < TT);
    unsigned nb0 = vb0 ? ald32(lbu + ((size_t)b * TT + pt0 - 1) * UP1 + u0) : 1u;
    unsigned ny0 = vy0 ? ald32(lyu + ((size_t)b * TT + pt0) * UU + (u0 - 1)) : 1u;
    unsigned nb1 = vb1 ? ald32(lbu + ((size_t)b * TT + pt1 - 1) * UP1 + u1) : 1u;
    unsigned ny1 = vy1 ? ald32(lyu + ((size_t)b * TT + pt1) * UU + (u1 - 1)) : 1u;

    for (int d = 1; d <= TT - 1 + UU; d++) {
      {
        int tries = 0;
        for (;;) {
          unsigned m = nb0 & ny0 & nb1 & ny1;
          if (__all((int)(m & 1u)) || ++tries > (1 << 15)) break;
          if (tries > 8) __builtin_amdgcn_s_sleep(8);
          int t0 = d - u0, t1 = d - u1;
          if (vb0) nb0 = ald32(lbu + ((size_t)b * TT + t0 - 1) * UP1 + u0);
          if (vy0) ny0 = ald32(lyu + ((size_t)b * TT + t0) * UU + (u0 - 1));
          if (vb1) nb1 = ald32(lbu + ((size_t)b * TT + t1 - 1) * UP1 + u1);
          if (vy1) ny1 = ald32(lyu + ((size_t)b * TT + t1) * UU + (u1 - 1));
        }
      }
      float lb0 = vb0 ? __uint_as_float(nb0 & ~1u) : 0.f;
      float ly0 = vy0 ? __uint_as_float(ny0 & ~1u) : 0.f;
      float lb1 = vb1 ? __uint_as_float(nb1 & ~1u) : 0.f;
      float ly1 = vy1 ? __uint_as_float(ny1 & ~1u) : 0.f;
      pt0 = (d + 1) - u0; pt1 = (d + 1) - u1;
      vb0 = (u0 <= UU && pt0 >= 1 && pt0 < TT);
      vy0 = (u0 >= 1 && u0 <= UU && pt0 >= 0 && pt0 < TT);
      vb1 = (u1 <= UU && pt1 >= 1 && pt1 < TT);
      vy1 = (u1 >= 1 && u1 <= UU && pt1 >= 0 && pt1 < TT);
      nb0 = vb0 ? ald32(lbu + ((size_t)b * TT + pt0 - 1) * UP1 + u0) : 1u;
      ny0 = vy0 ? ald32(lyu + ((size_t)b * TT + pt0) * UU + (u0 - 1)) : 1u;
      nb1 = vb1 ? ald32(lbu + ((size_t)b * TT + pt1 - 1) * UP1 + u1) : 1u;
      ny1 = vy1 ? ald32(lyu + ((size_t)b * TT + pt1) * UU + (u1 - 1)) : 1u;

      float am1 = __shfl_up(alpha1, 1);
      float old0 = alpha0, old1 = alpha1;
      int t0 = d - u0;
      if (u0 <= UU && t0 >= 0 && t0 < TT) {
        float a1 = (t0 >= 1) ? old0 + lb0 : NEG;
        float a2 = (u0 >= 1) ? am1 + ly0 : NEG;
        float m = fmaxf(a1, a2);
        float val = (m <= -1e29f) ? NEG : m + __logf(1.f + __expf(-fabsf(a1 - a2)));
        alpha0 = val;
        if (t0 == tl - 1 && u0 == ul) {
          unsigned lt; int tr = 0;
          for (;;) { lt = ald32(lbu + ((size_t)b * TT + t0) * UP1 + u0);
                     if ((lt & 1u) || ++tr > (1 << 15)) break;
                     __builtin_amdgcn_s_sleep(8); }
          atomicAdd(out, -0.125f * (val + __uint_as_float(lt & ~1u)));
        }
      }
      int t1 = d - u1;
      if (u1 <= UU && t1 >= 0 && t1 < TT) {
        float a1 = (t1 >= 1) ? old1 + lb1 : NEG;
        float a2 = old0 + ly1;                 // u1 odd => u1>=1 always
        float m = fmaxf(a1, a2);
        float val = (m <= -1e29f) ? NEG : m + __logf(1.f + __expf(-fabsf(a1 - a2)));
        alpha1 = val;
        if (t1 == tl - 1 && u1 == ul) {
          unsigned lt; int tr = 0;
          for (;;) { lt = ald32(lbu + ((size_t)b * TT + t1) * UP1 + u1);
                     if ((lt & 1u) || ++tr > (1 << 15)) break;
                     __builtin_amdgcn_s_sleep(8); }
          atomicAdd(out, -0.125f * (val + __uint_as_float(lt & ~1u)));
        }
      }
    }
    return;
  }

  if (wg >= 24) {
    // ================= LSE workers: cells c = w0, w0+224, ... (t-major) =================
    const int w0 = wg - 24;
    const unsigned* e2u = (const unsigned*)enc2;
    const unsigned* d2u = (const unsigned*)dec2;
    for (int c = w0; c < 4000; c += 224) {
      const int t = c >> 3, b = c & 7;
      const unsigned* er = e2u + ((size_t)t * 16 + b) * VV;
      unsigned ev0, ev1;
      {
        int tries = 0;
        for (;;) {
          ev0 = ald32(er + lane); ev1 = ald32(er + lane + 64);
          if (__all((int)(ev0 & ev1 & 1u)) || ++tries > (1 << 13)) break;
          backoff(tries);
        }
      }
      const float e0 = __uint_as_float(ev0 & ~1u);
      const float e1 = __uint_as_float(ev1 & ~1u);
      for (int u = wave; u < UP1; u += 8) {
        const unsigned* dr = d2u + ((size_t)u * 16 + b) * VV;
        unsigned dv0, dv1;
        int tr2 = 0;
        for (;;) {
          dv0 = ald32(dr + lane); dv1 = ald32(dr + lane + 64);
          if (__all((int)(dv0 & dv1 & 1u)) || ++tr2 > (1 << 13)) break;
          backoff(tr2);
        }
        float s0 = e0 + __uint_as_float(dv0 & ~1u);
        float s1 = e1 + __uint_as_float(dv1 & ~1u);
        float mx = fmaxf(s0, s1);
#pragma unroll
        for (int off = 32; off >= 1; off >>= 1) mx = fmaxf(mx, __shfl_xor(mx, off));
        float p = __expf(s0 - mx) + __expf(s1 - mx);
#pragma unroll
        for (int off = 32; off >= 1; off >>= 1) p += __shfl_xor(p, off);
        float lsev = mx + __logf(p);
        if (u < UU) {
          int y = ys[b * UU + u];              // in [1,127]
          float sy = (y < 64) ? __shfl(s0, y) : __shfl(s1, y - 64);
          if (lane == 0)
            ast32((unsigned*)(lyp + ((size_t)b * TT + t) * UU + u),
                  __float_as_uint(sy - lsev) | 1u);
        }
        if (lane == 0)
          ast32((unsigned*)(lbp + ((size_t)b * TT + t) * UP1 + u),
                __float_as_uint(s0 - lsev) | 1u);
      }
    }
    return;
  }

  // zero both LDS h buffers (pipeline branches only)
  for (int i = tid; i < 2 * 16 * 328; i += 512) ((ushort*)hbS)[i] = 0;

  if (wg >= 20) {
    // ================= streaming output projections (TAGGED outputs) =================
    const bool isenc = (wg < 23);
    const unsigned* hsrc = isenc ? h1u : hdu;
    const float* wsrc = isenc ? eWo : dWo;   // f32, converted on stage-in
    const float* bsrc = isenc ? ebo : dbo;
    float* osrc = isenc ? enc2 : dec2;
    const int tstart = isenc ? (wg - 20) : 0;
    const int tstep = isenc ? 3 : 1;
    const int tmax = isenc ? TT : UP1;
    ushort* wl = (ushort*)wlds;
    for (int i = tid; i < 40960; i += 512) wl[i] = f2bf(wsrc[i]);
    __syncthreads();
    const int nt = wave;                     // 8 col-tiles of 16
    const int vc = nt * 16 + n16;
    const float bias = bsrc[vc];
    s8v bf[10];
#pragma unroll
    for (int kt = 0; kt < 10; kt++)
      bf[kt] = *(const s8v*)(wl + (size_t)vc * HH + kt * 32 + q * 8);

    for (int t = tstart; t < tmax; t += tstep) {
      const unsigned* src = hsrc + (size_t)(t + 1) * 2560 + wave * 320 + lane;
      unsigned v[5];
#pragma unroll
      for (int j = 0; j < 5; j++) v[j] = ald32(src + j * 64);
      int tries = 0;
      for (;;) {
        unsigned a = v[0] & v[1] & v[2] & v[3] & v[4];
        if (__all((int)(a & 1u)) || ++tries > (1 << 17)) break;
        if (tries > 64) __builtin_amdgcn_s_sleep(1);
#pragma unroll
        for (int j = 0; j < 5; j++) v[j] = ald32(src + j * 64);
      }
#pragma unroll
      for (int j = 0; j < 5; j++) {
        int f = wave * 320 + j * 64 + lane;            // u = f>>3, b = f&7
        hbS[0][f & 7][f >> 3] = (ushort)(v[j] >> 16);
      }
      __syncthreads();
      s8v a[10];
#pragma unroll
      for (int kt = 0; kt < 10; kt++)
        a[kt] = *(const s8v*)&hbS[0][n16][kt * 32 + q * 8];
      f4v acc = {0.f, 0.f, 0.f, 0.f};
#pragma unroll
      for (int kt = 0; kt < 10; kt++)
        acc = __builtin_amdgcn_mfma_f32_16x16x32_bf16(a[kt], bf[kt], acc, 0, 0, 0);
      if (q < 2) {
#pragma unroll
        for (int r = 0; r < 4; r++) {
          int b = 4 * q + r;                 // D row = batch
          ast32((unsigned*)&osrc[((size_t)t * 16 + b) * VV + vc],
                __float_as_uint(acc[r] + bias) | 1u);
        }
      }
      __syncthreads();                       // before next t overwrites hbS
    }
    return;
  }

  if (wg >= 15) {
    // ================= relay: xp1[s] = Wih1 @ h0[s+1] + b1 =================
    const int rw = wg - 15;
    const int w = rw * 8 + wave;
    const int ubase = w * 8;
    s8v afr0[10];
    {
      const int arow0 = g * HH + ubase + uloc;
      const int arow1 = g * HH + ubase + 4 + uloc;
#pragma unroll
      for (int kt = 0; kt < 10; kt++) {
        afr0[kt] = ld8bf(eWih1 + (size_t)arow0 * HH + kt * 32 + q * 8);
        wlds[wave][kt][lane] = ld8bf(eWih1 + (size_t)arow1 * HH + kt * 32 + q * 8);
      }
    }
    f4v bias4[2];
#pragma unroll
    for (int tile = 0; tile < 2; tile++)
      bias4[tile] = *(const f4v*)(b1p + (ubase + tile * 4 + q) * 4);

    unsigned v[5];
    {
      const unsigned* p = h0u + 2560 + wave * 320 + lane;
#pragma unroll
      for (int j = 0; j < 5; j++) v[j] = ald32(p + j * 64);
    }
    __syncthreads();                         // weight-LDS + hbS zeros visible

    for (int s = 0; s < TT; s++) {
      const int pb = s & 1;
      {
        const unsigned* p = h0u + (size_t)(s + 1) * 2560 + wave * 320 + lane;
        int tries = 0;
        for (;;) {
          unsigned a = v[0] & v[1] & v[2] & v[3] & v[4];
          if (__all((int)(a & 1u)) || ++tries > (1 << 17)) break;
          if (tries > 64) __builtin_amdgcn_s_sleep(1);
#pragma unroll
          for (int j = 0; j < 5; j++) v[j] = ald32(p + j * 64);
        }
#pragma unroll
        for (int j = 0; j < 5; j++) {
          int f = wave * 320 + j * 64 + lane;          // u = f>>3, b = f&7
          hbS[pb][f & 7][f >> 3] = (ushort)(v[j] >> 16);
        }
      }
      __syncthreads();
      if (s + 1 < TT) {
        const unsigned* p = h0u + (size_t)(s + 2) * 2560 + wave * 320 + lane;
#pragma unroll
        for (int j = 0; j < 5; j++) v[j] = ald32(p + j * 64);
      }

      f4v acc[2];
      acc[0] = bias4[0]; acc[1] = bias4[1];
#pragma unroll
      for (int kt = 0; kt < 10; kt++) {
        s8v b = *(const s8v*)&hbS[pb][n16][kt * 32 + q * 8];
        acc[0] = __builtin_amdgcn_mfma_f32_16x16x32_bf16(afr0[kt], b, acc[0], 0, 0, 0);
        s8v a1 = wlds[wave][kt][lane];
        acc[1] = __builtin_amdgcn_mfma_f32_16x16x32_bf16(a1, b, acc[1], 0, 0, 0);
      }
      if (act) {
#pragma unroll
        for (int tile = 0; tile < 2; tile++) {
          unsigned* dp = xp1u + (size_t)((unsigned)s * 8u + (unsigned)n16) * G4
                       + (unsigned)((ubase + tile * 4 + q) * 4);
#pragma unroll
          for (int r = 0; r < 4; r++)
            ast32(dp + r, __float_as_uint(acc[tile][r]) | 1u);   // LSB tag on f32
        }
      }
    }
    return;
  }

  // ================= recurrent stages =================
  const int stage = wg / 5;
  const int gw = wg - stage * 5;
  const int w = gw * 8 + wave;              // wave-in-stage [0,40)
  const int ubase = w * 8;                  // this wave owns units [ubase, ubase+8)

  const float* Af = (stage == 0) ? eWhh0 : ((stage == 1) ? eWhh1 : dWhh);
  // tile0 -> regs (40 VGPR), tile1 -> LDS; converted inline from f32
  s8v afr0[10];
  {
    const int arow0 = g * HH + ubase + uloc;
    const int arow1 = g * HH + ubase + 4 + uloc;
#pragma unroll
    for (int kt = 0; kt < 10; kt++) {
      afr0[kt] = ld8bf(Af + (size_t)arow0 * HH + kt * 32 + q * 8);
      wlds[wave][kt][lane] = ld8bf(Af + (size_t)arow1 * HH + kt * 32 + q * 8);
    }
  }

  const int steps = (stage == 2) ? UP1 : TT;
  unsigned* hio = (stage == 0) ? h0u : ((stage == 1) ? h1u : hdu);

  const float* xq = 0;
  if (stage == 0)      xq = xp0 + (size_t)bcol * TT * G4;
  else if (stage == 2) xq = xpd + (size_t)bcol * UP1 * G4;

  float c0 = 0.f, c1 = 0.f;
  unsigned hv5[5];                           // in-flight bulk h reads
  __syncthreads();                           // LDS zeros + weight-LDS visible

  for (int t = 0; t < steps; t++) {
    const int pb = t & 1;

    // ---- pre-issue C-init inputs; consumed after the MFMA block ----
    f4v xq4[2];
    unsigned xv[2][4];
    if (stage != 1) {
#pragma unroll
      for (int tile = 0; tile < 2; tile++)
        xq4[tile] = *(const f4v*)(xq + (size_t)t * G4 + (ubase + tile * 4 + q) * 4);
    } else {
#pragma unroll
      for (int tile = 0; tile < 2; tile++) {
        const unsigned* xpp = xp1u + (size_t)((unsigned)t * 8u + (unsigned)bcol) * G4
                            + (unsigned)((ubase + tile * 4 + q) * 4);
#pragma unroll
        for (int r = 0; r < 4; r++) xv[tile][r] = ald32(xpp + r);
      }
    }

    // ---- resolve pre-issued bulk h[t] reads, transpose-relay into LDS ----
    if (t > 0) {
      const unsigned* src = hio + (size_t)t * 2560 + wave * 320 + lane;
      int tries = 0;
      for (;;) {
        unsigned a = hv5[0] & hv5[1] & hv5[2] & hv5[3] & hv5[4];
        if (__all((int)(a & 1u)) || ++tries > (1 << 17)) break;
        if (tries > 64) __builtin_amdgcn_s_sleep(1);
#pragma unroll
        for (int j = 0; j < 5; j++) hv5[j] = ald32(src + j * 64);
      }
#pragma unroll
      for (int j = 0; j < 5; j++) {
        int f = wave * 320 + j * 64 + lane;            // u = f>>3, b = f&7
        hbS[pb][f & 7][f >> 3] = (ushort)(hv5[j] >> 16);
      }
    }
    __syncthreads();

    // ---- MFMAs: B-frags from LDS h(t); tile1 A-frags from LDS ----
    f4v acc[2];
    acc[0] = (f4v){0.f, 0.f, 0.f, 0.f};
    acc[1] = (f4v){0.f, 0.f, 0.f, 0.f};
#pragma unroll
    for (int kt = 0; kt < 10; kt++) {
      s8v b = *(const s8v*)&hbS[pb][n16][kt * 32 + q * 8];
      acc[0] = __builtin_amdgcn_mfma_f32_16x16x32_bf16(afr0[kt], b, acc[0], 0, 0, 0);
      s8v a1 = wlds[wave][kt][lane];
      acc[1] = __builtin_amdgcn_mfma_f32_16x16x32_bf16(a1, b, acc[1], 0, 0, 0);
    }

    // ---- resolve C-init (deferred add; stage1 tag-spins on relay output) ----
    if (stage != 1) {
#pragma unroll
      for (int tile = 0; tile < 2; tile++) {
        acc[tile][0] += xq4[tile][0]; acc[tile][1] += xq4[tile][1];
        acc[tile][2] += xq4[tile][2]; acc[tile][3] += xq4[tile][3];
      }
    } else {
      int tries = 0;
      for (;;) {
        unsigned m = xv[0][0] & xv[0][1] & xv[0][2] & xv[0][3]
                   & xv[1][0] & xv[1][1] & xv[1][2] & xv[1][3];
        bool ok = (!act) || ((m & 1u) != 0u);
        if (__all((int)ok) || ++tries > (1 << 17)) break;
        if (tries > 64) __builtin_amdgcn_s_sleep(1);
#pragma unroll
        for (int tile = 0; tile < 2; tile++) {
          const unsigned* xpp = xp1u + (size_t)((unsigned)t * 8u + (unsigned)bcol) * G4
                              + (unsigned)((ubase + tile * 4 + q) * 4);
#pragma unroll
          for (int r = 0; r < 4; r++) xv[tile][r] = ald32(xpp + r);
        }
      }
#pragma unroll
      for (int tile = 0; tile < 2; tile++)
#pragma unroll
        for (int r = 0; r < 4; r++)
          acc[tile][r] += __uint_as_float(xv[tile][r] & ~1u);
    }

    // ---- lane-local LSTM cell ----
    float hv0, hv1;
    {
      float ig = sigf(acc[0][0]), fg = sigf(acc[0][1]);
      float gv = tanh_f(acc[0][2]), og = sigf(acc[0][3]);
      c0 = fg * c0 + ig * gv; hv0 = og * tanh_f(c0);
    }
    {
      float ig = sigf(acc[1][0]), fg = sigf(acc[1][1]);
      float gv = tanh_f(acc[1][2]), og = sigf(acc[1][3]);
      c1 = fg * c1 + ig * gv; hv1 = og * tanh_f(c1);
    }
    if (act) {
      // packed [u][b] store: wave's 16 stores span 2-4 cache lines; no drain
      unsigned* dst = hio + (size_t)(t + 1) * 2560;
      ast32(dst + (ubase + q) * 8 + n16,     (((unsigned)f2bf(hv0)) << 16) | 1u);
      ast32(dst + (ubase + 4 + q) * 8 + n16, (((unsigned)f2bf(hv1)) << 16) | 1u);
    }

    // ---- issue next step's bulk h reads: flight overlaps store landing ----
    if (t + 1 < steps) {
      const unsigned* src = hio + (size_t)(t + 1) * 2560 + wave * 320 + lane;
#pragma unroll
      for (int j = 0; j < 5; j++) hv5[j] = ald32(src + j * 64);
    }
  }
}

// ---------------- launch ----------------
extern "C" void kernel_launch(void* const* d_in, const int* in_sizes, int n_in,
                              void* d_out, int out_size, void* d_ws, size_t ws_size,
                              hipStream_t stream) {
  (void)in_sizes; (void)n_in; (void)out_size;
  const float* xs    = (const float*)d_in[0];
  const int*   ys    = (const int*)d_in[1];
  const int*   xlen  = (const int*)d_in[2];
  const int*   ylen  = (const int*)d_in[3];
  const float* eWih0 = (const float*)d_in[4];
  const float* eWhh0 = (const float*)d_in[5];
  const float* ebih0 = (const float*)d_in[6];
  const float* ebhh0 = (const float*)d_in[7];
  const float* eWih1 = (const float*)d_in[8];
  const float* eWhh1 = (const float*)d_in[9];
  const float* ebih1 = (const float*)d_in[10];
  const float* ebhh1 = (const float*)d_in[11];
  const float* eWo   = (const float*)d_in[12];
  const float* ebo   = (const float*)d_in[13];
  const float* dWih  = (const float*)d_in[15];
  const float* dWhh  = (const float*)d_in[16];
  const float* dbih  = (const float*)d_in[17];
  const float* dbhh  = (const float*)d_in[18];
  const float* dWo   = (const float*)d_in[19];
  const float* dbo   = (const float*)d_in[20];

  char* ws = (char*)d_ws;
  const size_t OFF_XP0   = 1024;
  const size_t OFF_XPD   = OFF_XP0   + 20480000;  // 8*500*1280 f32
  const size_t OFF_H0    = OFF_XPD   + 4956160;   // 501 * 2560 u32 (tagged, [u][b])
  const size_t OFF_H1    = OFF_H0    + 5130240;
  const size_t OFF_HD    = OFF_H1    + 5130240;   // 122 * 2560 u32
  const size_t OFF_WIH0B = OFF_HD    + 1249280;   // 1280*96 bf16
  const size_t OFF_XSB   = OFF_WIH0B + 245760;    // 4000*96 bf16
  const size_t OFF_B1P   = OFF_XSB   + 768000;
  const size_t OFF_B0S   = OFF_B1P   + 5120;
  const size_t OFF_ENC2  = OFF_B0S   + 5120;
  const size_t OFF_DEC2  = OFF_ENC2  + 4096000;   // 500*16*128 tagged f32
  const size_t OFF_LB    = OFF_DEC2  + 991232;    // 121*16*128 tagged f32
  const size_t OFF_LY    = OFF_LB    + 1936000;   // 8*500*121 tagged f32
  const size_t OFF_XP1   = OFF_LY    + 1920000;   // 500*8*1280 tagged f32
  const size_t TOTAL     = OFF_XP1   + 20480000;
  if (ws_size < TOTAL) return;

  float*    xp0   = (float*)(ws + OFF_XP0);
  float*    xpd   = (float*)(ws + OFF_XPD);
  unsigned* h0    = (unsigned*)(ws + OFF_H0);
  unsigned* h1    = (unsigned*)(ws + OFF_H1);
  unsigned* hd    = (unsigned*)(ws + OFF_HD);
  ushort*   wih0b = (ushort*)(ws + OFF_WIH0B);
  ushort*   xsb   = (ushort*)(ws + OFF_XSB);
  float*    b1p   = (float*)(ws + OFF_B1P);
  float*    b0s   = (float*)(ws + OFF_B0S);
  float*    enc2  = (float*)(ws + OFF_ENC2);
  float*    dec2  = (float*)(ws + OFF_DEC2);
  float*    lb    = (float*)(ws + OFF_LB);
  float*    ly    = (float*)(ws + OFF_LY);
  unsigned* xp1   = (unsigned*)(ws + OFF_XP1);
  float*    out   = (float*)d_out;

  hipLaunchKernelGGL(prep_w, dim3(2958), dim3(256), 0, stream,
                     eWih0, xs, ebih1, ebhh1, ebih0, ebhh0,
                     ys, dWih, dbih, dbhh,
                     wih0b, xsb, b1p, b0s, xpd, out);
  hipLaunchKernelGGL(xproj0_mfma, dim3(250), dim3(256), 0, stream, xsb, wih0b, b0s, xp0);
  hipLaunchKernelGGL(lstm_fused, dim3(256), dim3(512), 0, stream,
                     eWhh0, eWih1, eWhh1, dWhh, b1p, xp0, xpd, h0, h1, hd, xp1,
                     eWo, dWo, ebo, dbo, enc2, dec2, lb, ly,
                     ys, xlen, ylen, out);
}